// Round 11
// baseline (61.124 us; speedup 1.0000x reference)
//
#include <hip/hip_runtime.h>

#define NUM_GRAPHS 1024
#define BLOCK 256
#define TILE_NODES 1024                       // 4 nodes per thread per tile
#define TILES_PER_BLOCK 4
#define CHUNK (TILE_NODES * TILES_PER_BLOCK)  // 4096 contiguous nodes per block

// ---------------------------------------------------------------------------
// Fused kernel: segmented |pred-target| sums (sorted batch ids) + force-norm
// sum; last-arriving block finalizes. R6/R10 body unchanged. Handshake uses
// NO release fence: __syncthreads() already drains vmcnt(0) (compiler barrier
// semantics), all ws updates are device-scope atomics at the coherence point,
// so a RELAXED counter add ordered after the barrier suffices. (R9's ACQ_REL
// emitted buffer_wbl2 per block -> 977 L2 writebacks -> +22 us. Avoided.)
// ---------------------------------------------------------------------------
__global__ __launch_bounds__(BLOCK, 2) void mae_seg_kernel(
    const float* __restrict__ pred,
    const float* __restrict__ target,
    const int*   __restrict__ batch,
    const float* __restrict__ x,
    float* __restrict__ ws_sum,          // [NUM_GRAPHS]
    float* __restrict__ ws_cnt,          // [NUM_GRAPHS]
    float* __restrict__ ws_force,        // [1]
    unsigned int* __restrict__ ws_ctr,   // [1]
    float* __restrict__ out,
    int n)
{
    __shared__ float ls[NUM_GRAPHS];
    __shared__ float lc[NUM_GRAPHS];
    __shared__ float lf[BLOCK / 64];
    __shared__ int   s_last;

    const int tid      = threadIdx.x;
    const int node0    = blockIdx.x * CHUNK;
    if (node0 >= n) return;                    // safety (grid sized from n)
    const int node_end = min(node0 + CHUNK, n);

    // block's graph-id window (batch sorted) -> init/flush only this range
    const int b_lo = batch[node0];
    const int b_hi = batch[node_end - 1];
    for (int i = b_lo + tid; i <= b_hi; i += BLOCK) { ls[i] = 0.f; lc[i] = 0.f; }
    __syncthreads();

    const float4* p4 = (const float4*)pred;
    const float4* t4 = (const float4*)target;
    const int4*   b4 = (const int4*)batch;
    const float4* x4 = (const float4*)x;

    int   cur_id  = -1;
    float cur_sum = 0.f;
    float cur_cnt = 0.f;
    float fsum    = 0.f;

    // number of FULL tiles in this block's chunk (block-uniform)
    int ft = (node_end - node0) / TILE_NODES;  // 0..4; partial handled after

    // double-buffered tile registers (named -> static indexing)
    float4 PA[3], TA[3], XA[8]; int4 BA;
    float4 PB[3], TB[3], XB[8]; int4 BB;

#define LOAD_TILE(t, P, T, B, X)                                          \
    {                                                                     \
        const int g0 = (node0 + (t) * TILE_NODES) / 4 + tid;              \
        const int xb = (node0 + (t) * TILE_NODES) * 2;                    \
        P[0] = p4[g0 * 3 + 0]; P[1] = p4[g0 * 3 + 1]; P[2] = p4[g0 * 3 + 2]; \
        T[0] = t4[g0 * 3 + 0]; T[1] = t4[g0 * 3 + 1]; T[2] = t4[g0 * 3 + 2]; \
        B    = b4[g0];                                                    \
        X[0] = x4[xb + 0 * BLOCK + tid]; X[1] = x4[xb + 1 * BLOCK + tid]; \
        X[2] = x4[xb + 2 * BLOCK + tid]; X[3] = x4[xb + 3 * BLOCK + tid]; \
        X[4] = x4[xb + 4 * BLOCK + tid]; X[5] = x4[xb + 5 * BLOCK + tid]; \
        X[6] = x4[xb + 6 * BLOCK + tid]; X[7] = x4[xb + 7 * BLOCK + tid]; \
    }

#define CONSUME_TILE(P, T, B, X)                                          \
    {                                                                     \
        float4 pa = P[0], pb = P[1], pc = P[2];                           \
        float4 ta = T[0], tb = T[1], tc = T[2];                           \
        float asum[4];                                                    \
        asum[0] = fabsf(pa.x - ta.x) + fabsf(pa.y - ta.y) + fabsf(pa.z - ta.z); \
        asum[1] = fabsf(pa.w - ta.w) + fabsf(pb.x - tb.x) + fabsf(pb.y - tb.y); \
        asum[2] = fabsf(pb.z - tb.z) + fabsf(pb.w - tb.w) + fabsf(pc.x - tc.x); \
        asum[3] = fabsf(pc.y - tc.y) + fabsf(pc.z - tc.z) + fabsf(pc.w - tc.w); \
        int bid[4] = {B.x, B.y, B.z, B.w};                                \
        if (bid[0] == cur_id && bid[3] == cur_id) {                       \
            cur_sum += asum[0] + asum[1] + asum[2] + asum[3];             \
            cur_cnt += 4.f;                                               \
        } else {                                                          \
            _Pragma("unroll")                                             \
            for (int r = 0; r < 4; ++r) {                                 \
                if (bid[r] != cur_id) {                                   \
                    if (cur_id >= 0) {                                    \
                        atomicAdd(&ls[cur_id], cur_sum);                  \
                        atomicAdd(&lc[cur_id], cur_cnt);                  \
                    }                                                     \
                    cur_id = bid[r]; cur_sum = 0.f; cur_cnt = 0.f;        \
                }                                                         \
                cur_sum += asum[r];                                       \
                cur_cnt += 1.f;                                           \
            }                                                             \
        }                                                                 \
        _Pragma("unroll")                                                 \
        for (int v = 0; v < 8; ++v) {                                     \
            const float val = (tid & 1) ? X[v].x : X[v].w;                \
            const float oth = __shfl_xor(val, 1, 64);                     \
            fsum += sqrtf(val * val + oth * oth);                         \
        }                                                                 \
    }

    // ---- fully-unrolled 2-deep pipeline over full tiles ----
    if (ft >= 1) LOAD_TILE(0, PA, TA, BA, XA);
    if (ft >= 2) LOAD_TILE(1, PB, TB, BB, XB);
    if (ft >= 1) CONSUME_TILE(PA, TA, BA, XA);
    if (ft >= 3) LOAD_TILE(2, PA, TA, BA, XA);
    if (ft >= 2) CONSUME_TILE(PB, TB, BB, XB);
    if (ft >= 4) LOAD_TILE(3, PB, TB, BB, XB);
    if (ft >= 3) CONSUME_TILE(PA, TA, BA, XA);
    if (ft >= 4) CONSUME_TILE(PB, TB, BB, XB);

#undef LOAD_TILE
#undef CONSUME_TILE

    // ---- partial tail tile (at most one, last blocks only) ----
    {
        const int tnode0 = node0 + ft * TILE_NODES;
        if (tnode0 < node_end) {
            const int node = tnode0 + tid * 4;
            for (int r = 0; r < 4; ++r) {
                const int nd = node + r;
                if (nd >= n) break;
                float a = fabsf(pred[nd * 3 + 0] - target[nd * 3 + 0])
                        + fabsf(pred[nd * 3 + 1] - target[nd * 3 + 1])
                        + fabsf(pred[nd * 3 + 2] - target[nd * 3 + 2]);
                int b = batch[nd];
                if (b != cur_id) {
                    if (cur_id >= 0) {
                        atomicAdd(&ls[cur_id], cur_sum);
                        atomicAdd(&lc[cur_id], cur_cnt);
                    }
                    cur_id = b; cur_sum = 0.f; cur_cnt = 0.f;
                }
                cur_sum += a;
                cur_cnt += 1.f;
            }
            const int xb  = tnode0 * 2;
            const int nx4 = n * 2;
#pragma unroll
            for (int v = 0; v < 8; ++v) {
                const int idx = xb + v * BLOCK + tid;
                float val = 0.f;
                if (idx < nx4) {
                    float4 xv = x4[idx];
                    val = (tid & 1) ? xv.x : xv.w;
                }
                const float oth = __shfl_xor(val, 1, 64);
                fsum += sqrtf(val * val + oth * oth);   // OOB contributes 0
            }
        }
    }

    // ---- wave-aggregated flush of the final run ----
    {
        const int id0 = __shfl(cur_id, 0, 64);
        if (__all(cur_id == id0)) {
            float s = cur_sum, c = cur_cnt;
#pragma unroll
            for (int off = 32; off > 0; off >>= 1) {
                s += __shfl_xor(s, off, 64);
                c += __shfl_xor(c, off, 64);
            }
            if ((tid & 63) == 0 && id0 >= 0) {
                atomicAdd(&ls[id0], s);
                atomicAdd(&lc[id0], c);
            }
        } else if (cur_id >= 0) {
            atomicAdd(&ls[cur_id], cur_sum);
            atomicAdd(&lc[cur_id], cur_cnt);
        }
    }

    // ---- force: block reduce (each row norm counted by both lanes) ----
    fsum *= 0.5f;
#pragma unroll
    for (int off = 32; off > 0; off >>= 1) fsum += __shfl_down(fsum, off, 64);
    if ((tid & 63) == 0) lf[tid >> 6] = fsum;
    __syncthreads();
    if (tid == 0) {
        atomicAdd(ws_force, lf[0] + lf[1] + lf[2] + lf[3]);
    }

    // ---- flush per-block LDS partials (only the touched id window) ----
    for (int i = b_lo + tid; i <= b_hi; i += BLOCK) {
        float c = lc[i];
        if (c != 0.f) {
            atomicAdd(&ws_sum[i], ls[i]);
            atomicAdd(&ws_cnt[i], c);
        }
    }

    // ---- completion handshake (NO release fence) ----
    // __syncthreads() semantics drain vmcnt(0) for every wave in the block,
    // so all our device-scope atomics are at the coherence point before the
    // relaxed counter increment below.
    __syncthreads();
    if (tid == 0) {
        unsigned prev = __hip_atomic_fetch_add(ws_ctr, 1u, __ATOMIC_RELAXED,
                                               __HIP_MEMORY_SCOPE_AGENT);
        s_last = (prev == gridDim.x - 1) ? 1 : 0;
    }
    __syncthreads();
    if (!s_last) return;

    // last-arriving block: all other blocks' atomics are visible at the
    // coherence point; read via agent-scope atomic loads.
    float part = 0.f;
    for (int i = tid; i < NUM_GRAPHS; i += BLOCK) {
        float s = __hip_atomic_load(&ws_sum[i], __ATOMIC_RELAXED, __HIP_MEMORY_SCOPE_AGENT);
        float c = __hip_atomic_load(&ws_cnt[i], __ATOMIC_RELAXED, __HIP_MEMORY_SCOPE_AGENT);
        part += s / (fmaxf(c, 1.0f) * 3.0f);
    }
#pragma unroll
    for (int off = 32; off > 0; off >>= 1) part += __shfl_down(part, off, 64);
    __syncthreads();                        // lf reuse safe
    if ((tid & 63) == 0) lf[tid >> 6] = part;
    __syncthreads();
    if (tid == 0) {
        float tot   = lf[0] + lf[1] + lf[2] + lf[3];
        float force = __hip_atomic_load(ws_force, __ATOMIC_RELAXED, __HIP_MEMORY_SCOPE_AGENT);
        float scale = fmaxf(force, 0.1f);
        out[0] = (tot / (float)NUM_GRAPHS) * scale * 100.0f;
    }
}

extern "C" void kernel_launch(void* const* d_in, const int* in_sizes, int n_in,
                              void* d_out, int out_size, void* d_ws, size_t ws_size,
                              hipStream_t stream) {
    const float* pred   = (const float*)d_in[0];
    const float* target = (const float*)d_in[1];
    const int*   batch  = (const int*)d_in[2];
    const float* x      = (const float*)d_in[3];
    float* out = (float*)d_out;

    const int n = in_sizes[2];                  // N nodes (batch vector length)

    float* ws_sum        = (float*)d_ws;        // [1024]
    float* ws_cnt        = ws_sum + NUM_GRAPHS; // [1024]
    float* ws_force      = ws_cnt + NUM_GRAPHS; // [1]
    unsigned int* ws_ctr = (unsigned int*)(ws_force + 1);  // [1]

    hipMemsetAsync(d_ws, 0, (2 * NUM_GRAPHS + 2) * sizeof(float), stream);

    const int blocks = (n + CHUNK - 1) / CHUNK;
    mae_seg_kernel<<<blocks, BLOCK, 0, stream>>>(pred, target, batch, x,
                                                 ws_sum, ws_cnt, ws_force, ws_ctr,
                                                 out, n);
}

// Round 12
// 51.269 us; speedup vs baseline: 1.1922x; 1.1922x over previous
//
#include <hip/hip_runtime.h>

#define NUM_GRAPHS 1024
#define BLOCK 256
#define TILE_NODES 1024                       // 4 nodes per thread per tile
#define TILES_PER_BLOCK 4
#define CHUNK (TILE_NODES * TILES_PER_BLOCK)  // 4096 contiguous nodes per block

// ---------------------------------------------------------------------------
// Kernel 1: segmented |pred-target| sums (sorted batch ids) + force-norm sum.
// Persistent chunked blocks; explicit 2-deep double-buffered load pipeline
// (LOAD(t+1) issued before CONSUME(t)). Best-known configuration (R6/R10,
// reproduced 51.2/51.3 us).
//
// Session rules distilled (R1-R11):
//  - Coalesced float4 + shfl_xor pairing beats strided scalar loads 4.5x.
//  - Per-block cross-XCD coordination (threadfence / ACQ_REL / even RELAXED
//    counter RMW + fused finalize) costs 10-22 us across ~1000 blocks;
//    a separate 2 us finalize dispatch is strictly cheaper.
//  - Kernel time is insensitive to occupancy, MLP depth, NT policy, and
//    data residency (L3-resident replays identical) -> per-CU vector-memory
//    request-path wall at ~81-84% of the 6.29 TB/s copy ceiling.
// ---------------------------------------------------------------------------
__global__ __launch_bounds__(BLOCK, 2) void mae_seg_kernel(
    const float* __restrict__ pred,
    const float* __restrict__ target,
    const int*   __restrict__ batch,
    const float* __restrict__ x,
    float* __restrict__ ws_sum,    // [NUM_GRAPHS]
    float* __restrict__ ws_cnt,    // [NUM_GRAPHS]
    float* __restrict__ ws_force,  // [1]
    int n)
{
    __shared__ float ls[NUM_GRAPHS];
    __shared__ float lc[NUM_GRAPHS];
    __shared__ float lf[BLOCK / 64];

    const int tid      = threadIdx.x;
    const int node0    = blockIdx.x * CHUNK;
    if (node0 >= n) return;                    // safety (grid sized from n)
    const int node_end = min(node0 + CHUNK, n);

    // block's graph-id window (batch sorted) -> init/flush only this range
    const int b_lo = batch[node0];
    const int b_hi = batch[node_end - 1];
    for (int i = b_lo + tid; i <= b_hi; i += BLOCK) { ls[i] = 0.f; lc[i] = 0.f; }
    __syncthreads();

    const float4* p4 = (const float4*)pred;
    const float4* t4 = (const float4*)target;
    const int4*   b4 = (const int4*)batch;
    const float4* x4 = (const float4*)x;

    int   cur_id  = -1;
    float cur_sum = 0.f;
    float cur_cnt = 0.f;
    float fsum    = 0.f;

    // number of FULL tiles in this block's chunk (block-uniform)
    int ft = (node_end - node0) / TILE_NODES;  // 0..4; partial handled after

    // double-buffered tile registers (named -> static indexing)
    float4 PA[3], TA[3], XA[8]; int4 BA;
    float4 PB[3], TB[3], XB[8]; int4 BB;

#define LOAD_TILE(t, P, T, B, X)                                          \
    {                                                                     \
        const int g0 = (node0 + (t) * TILE_NODES) / 4 + tid;              \
        const int xb = (node0 + (t) * TILE_NODES) * 2;                    \
        P[0] = p4[g0 * 3 + 0]; P[1] = p4[g0 * 3 + 1]; P[2] = p4[g0 * 3 + 2]; \
        T[0] = t4[g0 * 3 + 0]; T[1] = t4[g0 * 3 + 1]; T[2] = t4[g0 * 3 + 2]; \
        B    = b4[g0];                                                    \
        X[0] = x4[xb + 0 * BLOCK + tid]; X[1] = x4[xb + 1 * BLOCK + tid]; \
        X[2] = x4[xb + 2 * BLOCK + tid]; X[3] = x4[xb + 3 * BLOCK + tid]; \
        X[4] = x4[xb + 4 * BLOCK + tid]; X[5] = x4[xb + 5 * BLOCK + tid]; \
        X[6] = x4[xb + 6 * BLOCK + tid]; X[7] = x4[xb + 7 * BLOCK + tid]; \
    }

#define CONSUME_TILE(P, T, B, X)                                          \
    {                                                                     \
        float4 pa = P[0], pb = P[1], pc = P[2];                           \
        float4 ta = T[0], tb = T[1], tc = T[2];                           \
        float asum[4];                                                    \
        asum[0] = fabsf(pa.x - ta.x) + fabsf(pa.y - ta.y) + fabsf(pa.z - ta.z); \
        asum[1] = fabsf(pa.w - ta.w) + fabsf(pb.x - tb.x) + fabsf(pb.y - tb.y); \
        asum[2] = fabsf(pb.z - tb.z) + fabsf(pb.w - tb.w) + fabsf(pc.x - tc.x); \
        asum[3] = fabsf(pc.y - tc.y) + fabsf(pc.z - tc.z) + fabsf(pc.w - tc.w); \
        int bid[4] = {B.x, B.y, B.z, B.w};                                \
        if (bid[0] == cur_id && bid[3] == cur_id) {                       \
            cur_sum += asum[0] + asum[1] + asum[2] + asum[3];             \
            cur_cnt += 4.f;                                               \
        } else {                                                          \
            _Pragma("unroll")                                             \
            for (int r = 0; r < 4; ++r) {                                 \
                if (bid[r] != cur_id) {                                   \
                    if (cur_id >= 0) {                                    \
                        atomicAdd(&ls[cur_id], cur_sum);                  \
                        atomicAdd(&lc[cur_id], cur_cnt);                  \
                    }                                                     \
                    cur_id = bid[r]; cur_sum = 0.f; cur_cnt = 0.f;        \
                }                                                         \
                cur_sum += asum[r];                                       \
                cur_cnt += 1.f;                                           \
            }                                                             \
        }                                                                 \
        _Pragma("unroll")                                                 \
        for (int v = 0; v < 8; ++v) {                                     \
            const float val = (tid & 1) ? X[v].x : X[v].w;                \
            const float oth = __shfl_xor(val, 1, 64);                     \
            fsum += sqrtf(val * val + oth * oth);                         \
        }                                                                 \
    }

    // ---- fully-unrolled 2-deep pipeline over full tiles ----
    if (ft >= 1) LOAD_TILE(0, PA, TA, BA, XA);
    if (ft >= 2) LOAD_TILE(1, PB, TB, BB, XB);
    if (ft >= 1) CONSUME_TILE(PA, TA, BA, XA);
    if (ft >= 3) LOAD_TILE(2, PA, TA, BA, XA);
    if (ft >= 2) CONSUME_TILE(PB, TB, BB, XB);
    if (ft >= 4) LOAD_TILE(3, PB, TB, BB, XB);
    if (ft >= 3) CONSUME_TILE(PA, TA, BA, XA);
    if (ft >= 4) CONSUME_TILE(PB, TB, BB, XB);

#undef LOAD_TILE
#undef CONSUME_TILE

    // ---- partial tail tile (at most one, last blocks only) ----
    {
        const int tnode0 = node0 + ft * TILE_NODES;
        if (tnode0 < node_end) {
            const int node = tnode0 + tid * 4;
            for (int r = 0; r < 4; ++r) {
                const int nd = node + r;
                if (nd >= n) break;
                float a = fabsf(pred[nd * 3 + 0] - target[nd * 3 + 0])
                        + fabsf(pred[nd * 3 + 1] - target[nd * 3 + 1])
                        + fabsf(pred[nd * 3 + 2] - target[nd * 3 + 2]);
                int b = batch[nd];
                if (b != cur_id) {
                    if (cur_id >= 0) {
                        atomicAdd(&ls[cur_id], cur_sum);
                        atomicAdd(&lc[cur_id], cur_cnt);
                    }
                    cur_id = b; cur_sum = 0.f; cur_cnt = 0.f;
                }
                cur_sum += a;
                cur_cnt += 1.f;
            }
            const int xb  = tnode0 * 2;
            const int nx4 = n * 2;
#pragma unroll
            for (int v = 0; v < 8; ++v) {
                const int idx = xb + v * BLOCK + tid;
                float val = 0.f;
                if (idx < nx4) {
                    float4 xv = x4[idx];
                    val = (tid & 1) ? xv.x : xv.w;
                }
                const float oth = __shfl_xor(val, 1, 64);
                fsum += sqrtf(val * val + oth * oth);   // OOB contributes 0
            }
        }
    }

    // ---- wave-aggregated flush of the final run ----
    {
        const int id0 = __shfl(cur_id, 0, 64);
        if (__all(cur_id == id0)) {
            float s = cur_sum, c = cur_cnt;
#pragma unroll
            for (int off = 32; off > 0; off >>= 1) {
                s += __shfl_xor(s, off, 64);
                c += __shfl_xor(c, off, 64);
            }
            if ((tid & 63) == 0 && id0 >= 0) {
                atomicAdd(&ls[id0], s);
                atomicAdd(&lc[id0], c);
            }
        } else if (cur_id >= 0) {
            atomicAdd(&ls[cur_id], cur_sum);
            atomicAdd(&lc[cur_id], cur_cnt);
        }
    }

    // ---- force: block reduce (each row norm counted by both lanes) ----
    fsum *= 0.5f;
#pragma unroll
    for (int off = 32; off > 0; off >>= 1) fsum += __shfl_down(fsum, off, 64);
    if ((tid & 63) == 0) lf[tid >> 6] = fsum;
    __syncthreads();
    if (tid == 0) {
        atomicAdd(ws_force, lf[0] + lf[1] + lf[2] + lf[3]);
    }

    // ---- flush per-block LDS partials (only the touched id window) ----
    for (int i = b_lo + tid; i <= b_hi; i += BLOCK) {
        float c = lc[i];
        if (c != 0.f) {
            atomicAdd(&ws_sum[i], ls[i]);
            atomicAdd(&ws_cnt[i], c);
        }
    }
}

// ---------------------------------------------------------------------------
// Kernel 2: finalize — mean over graphs of seg_sum/(max(cnt,1)*3), scale.
// ---------------------------------------------------------------------------
__global__ __launch_bounds__(NUM_GRAPHS) void finalize_kernel(
    const float* __restrict__ ws_sum,
    const float* __restrict__ ws_cnt,
    const float* __restrict__ ws_force,
    float* __restrict__ out)
{
    __shared__ float red[NUM_GRAPHS];
    const int t = threadIdx.x;
    red[t] = ws_sum[t] / (fmaxf(ws_cnt[t], 1.0f) * 3.0f);
    __syncthreads();
    for (int s = NUM_GRAPHS / 2; s > 0; s >>= 1) {
        if (t < s) red[t] += red[t + s];
        __syncthreads();
    }
    if (t == 0) {
        const float scale = fmaxf(ws_force[0], 0.1f);
        out[0] = (red[0] / (float)NUM_GRAPHS) * scale * 100.0f;
    }
}

extern "C" void kernel_launch(void* const* d_in, const int* in_sizes, int n_in,
                              void* d_out, int out_size, void* d_ws, size_t ws_size,
                              hipStream_t stream) {
    const float* pred   = (const float*)d_in[0];
    const float* target = (const float*)d_in[1];
    const int*   batch  = (const int*)d_in[2];
    const float* x      = (const float*)d_in[3];
    float* out = (float*)d_out;

    const int n = in_sizes[2];                  // N nodes (batch vector length)

    float* ws_sum   = (float*)d_ws;             // [1024]
    float* ws_cnt   = ws_sum + NUM_GRAPHS;      // [1024]
    float* ws_force = ws_cnt + NUM_GRAPHS;      // [1]

    hipMemsetAsync(d_ws, 0, (2 * NUM_GRAPHS + 1) * sizeof(float), stream);

    const int blocks = (n + CHUNK - 1) / CHUNK;
    mae_seg_kernel<<<blocks, BLOCK, 0, stream>>>(pred, target, batch, x,
                                                 ws_sum, ws_cnt, ws_force, n);
    finalize_kernel<<<1, NUM_GRAPHS, 0, stream>>>(ws_sum, ws_cnt, ws_force, out);
}